// Round 4
// baseline (409.027 us; speedup 1.0000x reference)
//
#include <hip/hip_runtime.h>

// ViTPose attention, B=16 N=1024 C=1024 H=16 D=64, fp32 in/out.
// bf16 MFMA pipeline: cast/transpose -> QKV GEMM -> flash attention (S^T form) -> proj GEMM.
// R9: de-risked R8. GEMM 256x128 tile, 8 waves, counted-vmcnt K-pipeline:
// A TRIPLE-buffered, B DOUBLE-buffered (128 KB LDS total — the proven size).
// Per iter: issue B(t+1) then A(t+2) (order pinned by sched_barrier), compute
// tile t, then s_waitcnt vmcnt(4) + raw s_barrier — drains {A(t+1),B(t+1)},
// A(t+2) flies across the barrier (never vmcnt(0) mid-loop). Wave tile 64x64:
// fragment math / XOR swizzle identical to verified R7. Attn unchanged (R7).

#define BB 16
#define NN 1024
#define CC 1024
#define HH 16
#define DD 64
#define BN (BB * NN)          // 16384 tokens
#define HEADELEMS (256 * 1024 * 64)  // 16777216 elems per Q/K/V region

typedef float  f4     __attribute__((ext_vector_type(4)));
typedef __bf16 bf16x8 __attribute__((ext_vector_type(8)));
typedef __bf16 bf16x4 __attribute__((ext_vector_type(4)));
typedef short  s8v    __attribute__((ext_vector_type(8)));
typedef short  s4v    __attribute__((ext_vector_type(4)));
typedef short  s2v    __attribute__((ext_vector_type(2)));

#if __has_builtin(__builtin_amdgcn_exp2f)
#define EXP2(x) __builtin_amdgcn_exp2f(x)
#else
#define EXP2(x) exp2f(x)
#endif

__device__ __forceinline__ short f2bf(float x) {
  union { float f; unsigned u; } a; a.f = x;
  unsigned r = a.u + 0x7fffu + ((a.u >> 16) & 1u);   // RNE truncate (finite inputs)
  return (short)(r >> 16);
}

__device__ __forceinline__ void gl_lds16(const void* g, void* l) {
  __builtin_amdgcn_global_load_lds((__attribute__((address_space(1))) void*)g,
                                   (__attribute__((address_space(3))) void*)l,
                                   16, 0, 0);
}

__device__ __forceinline__ f4 mfma16(bf16x8 a, bf16x8 b, f4 c) {
  return __builtin_amdgcn_mfma_f32_16x16x32_bf16(a, b, c, 0, 0, 0);
}

// ---------------- elementwise fp32 -> bf16 cast ----------------
__global__ void cast_bf16(const float* __restrict__ x, short* __restrict__ y) {
  int i = (blockIdx.x * 256 + threadIdx.x) * 4;
  float4 v = *(const float4*)&x[i];
  s4v o;
  o[0] = f2bf(v.x); o[1] = f2bf(v.y); o[2] = f2bf(v.z); o[3] = f2bf(v.w);
  *(s4v*)&y[i] = o;
}

// ---------------- W [K][Nw] fp32 -> Wt [Nw][K] bf16 ----------------
__global__ void transpose_cast(const float* __restrict__ W, short* __restrict__ Wt,
                               int K, int Nw) {
  __shared__ float tile[32][33];
  int bx = blockIdx.x, by = blockIdx.y;
  int t = threadIdx.x;
  int tc = t & 31, tr = t >> 5;   // tr 0..7
#pragma unroll
  for (int i = 0; i < 4; ++i) {
    int r = tr + i * 8;
    tile[r][tc] = W[(size_t)(by * 32 + r) * Nw + bx * 32 + tc];
  }
  __syncthreads();
#pragma unroll
  for (int i = 0; i < 4; ++i) {
    int r = tr + i * 8;
    Wt[(size_t)(bx * 32 + r) * K + by * 32 + tc] = f2bf(tile[tc][r]);
  }
}

// ---------------- bf16 GEMM: C[M][N] = A[M][K] * Bt[N][K]^T + bias ----------------
// 256x128 block tile, BK=64, 512 threads = 8 waves in 4x2 of 64x64.
// A loads: 4/thread/tile, B loads: 2/thread/tile.
// Steady state at end-of-iter barrier: outstanding (oldest first) =
//   A(t+1)[4] B(t+1)[2] A(t+2)[4]  -> s_waitcnt vmcnt(4) retires tile t+1,
//   A(t+2) crosses the raw s_barrier. Counted, never 0 mid-loop (T4).
// Staging: 8-row groups, linear LDS dest, inverse-swizzled source (chunk^row&7).
// Block swizzle: XCD-chunked, 4x8 panel sub-blocks (needs GX%4==0, GY==64).
#define GSTAGE_A(buf, kb)                                                      \
  {                                                                            \
    _Pragma("unroll")                                                          \
    for (int rblk = 0; rblk < 4; ++rblk) {                                     \
      int rbase = (w * 4 + rblk) * 8;                                          \
      gl_lds16(A + (size_t)(row0 + rbase + sr8) * K + (kb) + sc8 * 8,          \
               &la[buf][rbase * 64]);                                          \
    }                                                                          \
  }
#define GSTAGE_B(buf, kb)                                                      \
  {                                                                            \
    _Pragma("unroll")                                                          \
    for (int bblk = 0; bblk < 2; ++bblk) {                                     \
      int rbase = (w * 2 + bblk) * 8;                                          \
      gl_lds16(Bt + (size_t)(col0 + rbase + sr8) * K + (kb) + sc8 * 8,         \
               &lb[buf][rbase * 64]);                                          \
    }                                                                          \
  }

template <int EPI>
__global__ __launch_bounds__(512, 1)
void gemm_bt(const short* __restrict__ A, const short* __restrict__ Bt,
             const float* __restrict__ bias, float* __restrict__ Cf,
             short* __restrict__ Cq, int M, int N, int K) {
  __shared__ short la[3][256 * 64];   // 96 KB
  __shared__ short lb[2][128 * 64];   // 32 KB  (total 128 KB)
  const int t = threadIdx.x, lane = t & 63, w = t >> 6;
  // XCD-chunked swizzle + 4x8 panel sub-blocking (bijective for GX%4==0, GY=64)
  int bid = blockIdx.y * gridDim.x + blockIdx.x;
  int xcd = bid & 7, sub = bid >> 3;
  int grp = sub >> 5, rem = sub & 31;
  int xb = grp * 4 + (rem & 3), yb = xcd * 8 + (rem >> 2);
  const int row0 = yb * 256, col0 = xb * 128;
  const int wm = (w >> 1) * 64, wn = (w & 1) * 64;
  const int q = lane >> 4, ln = lane & 15;
  const int sr8 = lane >> 3;         // local row within 8-row group
  const int sc8 = (lane & 7) ^ sr8;  // global 16B chunk (xor swizzle)
  f4 acc[4][4] = {};

  const int NT = K >> 6;
  // prologue: A(0), B(0) fully; A(1) in flight across the first barrier
  GSTAGE_A(0, 0);
  GSTAGE_B(0, 0);
  __builtin_amdgcn_sched_barrier(0);
  GSTAGE_A(1, 64);
  asm volatile("s_waitcnt vmcnt(4)" ::: "memory");   // A(0)+B(0) landed
  __builtin_amdgcn_s_barrier();
  __builtin_amdgcn_sched_barrier(0);

  int curA = 0;
  for (int tt = 0; tt < NT; ++tt) {
    // issue B(t+1) then A(t+2); order pinned so the vmcnt count is exact
    if (tt + 1 < NT) GSTAGE_B((tt + 1) & 1, (tt + 1) * 64);
    __builtin_amdgcn_sched_barrier(0);
    if (tt + 2 < NT) {
      int a2 = curA + 2; if (a2 >= 3) a2 -= 3;
      GSTAGE_A(a2, (tt + 2) * 64);
    }
    __builtin_amdgcn_sched_barrier(0);
#pragma unroll
    for (int ks2 = 0; ks2 < 2; ++ks2) {
      const int c8 = ks2 * 4 + q;
      const int swz = (c8 ^ (ln & 7)) * 8;   // swizzled chunk offset (shorts)
      bf16x8 af[4], bfr[4];
#pragma unroll
      for (int i = 0; i < 4; ++i) {
        af[i]  = *(const bf16x8*)&la[curA][(wm + i * 16 + ln) * 64 + swz];
        bfr[i] = *(const bf16x8*)&lb[tt & 1][(wn + i * 16 + ln) * 64 + swz];
      }
      __builtin_amdgcn_s_setprio(1);
#pragma unroll
      for (int i = 0; i < 4; ++i)
#pragma unroll
        for (int j = 0; j < 4; ++j)
          acc[i][j] = mfma16(af[i], bfr[j], acc[i][j]);
      __builtin_amdgcn_s_setprio(0);
    }
    if (tt + 2 < NT) asm volatile("s_waitcnt vmcnt(4)" ::: "memory");
    else             asm volatile("s_waitcnt vmcnt(0)" ::: "memory");
    __builtin_amdgcn_s_barrier();
    __builtin_amdgcn_sched_barrier(0);
    curA = (curA == 2) ? 0 : curA + 1;
  }

#pragma unroll
  for (int i = 0; i < 4; ++i) {
    int rbase = row0 + wm + i * 16 + q * 4;
#pragma unroll
    for (int j = 0; j < 4; ++j) {
      int col = col0 + wn + j * 16 + ln;
      float bv = bias[col];
      if (EPI == 0) {
#pragma unroll
        for (int r2 = 0; r2 < 4; ++r2)
          Cf[(size_t)(rbase + r2) * N + col] = acc[i][j][r2] + bv;
      } else {
        int which = col >> 10, c = col & 1023;
        int h = c >> 6, d = c & 63;
        if (which == 2) {
          // V -> transposed layout [bh][d][n]; 4 consecutive tokens = s4v store
          int bh = (rbase >> 10) * HH + h;
          s4v vv;
#pragma unroll
          for (int r2 = 0; r2 < 4; ++r2) vv[r2] = f2bf(acc[i][j][r2] + bv);
          *(s4v*)&Cq[(size_t)2 * HEADELEMS + ((size_t)bh * DD + d) * NN + (rbase & 1023)] = vv;
        } else {
          float scale = (which == 0) ? 0.1803368801f : 1.0f;  // (1/8)*log2(e) for Q
#pragma unroll
          for (int r2 = 0; r2 < 4; ++r2) {
            int row = rbase + r2;                       // token
            int bh = (row >> 10) * HH + h;
            size_t idx = ((size_t)bh * NN + (row & 1023)) * DD + d;
            Cq[(size_t)which * HEADELEMS + idx] = f2bf((acc[i][j][r2] + bv) * scale);
          }
        }
      }
    }
  }
}

// ---------------- flash attention, S^T form, fixed-max softmax ----------------
// grid (256 bh, 4 qb). 512 threads = 8 waves; each wave owns 32 q rows
// (2 groups of 16 -> every K/V/P fragment read feeds 2 MFMAs).
// All LDS tiles: linear 64-short rows, 16B chunks XOR-swizzled by (row&7);
// every fragment row is 16k+ln so the swizzle is the lane constant ln&7.
// K from Km [bh][n][d]; V from Vt [bh][d][n] (written by QKV epilogue).
// K/V double-buffered, prefetch issued before compute, ONE barrier per kt.
// Scores carry (1/8)*log2e from Q pre-scale; fixed max=0 softmax (|s|<=~9).
__global__ __launch_bounds__(512, 4)
void attn(const short* __restrict__ Qg, const short* __restrict__ Kg,
          const short* __restrict__ Vtg, short* __restrict__ ctx) {
  __shared__ short sQP[256 * 64];     // 32 KB: Q tile at start, then P (wave-private rows)
  __shared__ short sK[2][64 * 64];    // 16 KB
  __shared__ short sV[2][64 * 64];    // 16 KB: V^T tile, row=d, col=m(key)
  const int t = threadIdx.x, lane = t & 63, w = t >> 6;
  const int bh = blockIdx.x, qb = blockIdx.y;
  const short* Qh = Qg + (size_t)bh * (NN * DD) + qb * 256 * DD;
  const short* Kh = Kg + (size_t)bh * (NN * DD);
  const short* Vh = Vtg + (size_t)bh * (NN * DD);   // [d][n]

  // --- stage Q tile [256][64]: 2048 chunks, DMA, inverse-swizzled source ---
#pragma unroll
  for (int k = 0; k < 4; ++k) {
    int i = t + k * 512;
    int r = i >> 3, c = i & 7;
    gl_lds16(Qh + r * DD + ((c ^ (r & 7)) * 8), &sQP[i * 8]);
  }
  // --- stage K/V tile 0 (512 chunks each, 1 per thread) ---
  const int sr = t >> 3, sc = t & 7;
  const int ssc = ((sc ^ (sr & 7)) * 8);      // swizzled chunk offset (shorts)
  gl_lds16(Kh + sr * DD + ssc, &sK[0][t * 8]);
  gl_lds16(Vh + (size_t)sr * NN + ssc, &sV[0][t * 8]);

  __syncthreads();   // drains vmcnt: Q + tile0 resident

  const int q = lane >> 4, ln = lane & 15;
  const int wq = w * 32;          // this wave's 32 query rows
  const int sw = ln & 7;          // fragment-row chunk swizzle

  // hoist Q fragments (own rows only); frees sQP for P
  bf16x8 qf[2][2];
#pragma unroll
  for (int ks = 0; ks < 2; ++ks)
#pragma unroll
    for (int g = 0; g < 2; ++g)
      qf[ks][g] = *(const bf16x8*)&sQP[(wq + g * 16 + ln) * 64 + (((ks * 4 + q) ^ sw) * 8)];

  f4 o[2][4] = {};                // O[g][j]: row=q*4+r (query), col=j*16+ln (d)
  float lsum0 = 0.f, lsum1 = 0.f; // per-lane partial sums of exp2(s), per group

  for (int kt = 0; kt < 16; ++kt) {
    const int cur = kt & 1;
    // prefetch next K/V tile into the other buffer (drained by end barrier)
    if (kt < 15) {
      const int nb = cur ^ 1;
      gl_lds16(Kh + (kt + 1) * 64 * DD + sr * DD + ssc, &sK[nb][t * 8]);
      gl_lds16(Vh + (size_t)sr * NN + (kt + 1) * 64 + ssc, &sV[nb][t * 8]);
    }

    // S^T = K Q^T : s[ki][g] has key row = ki*16+q*4+r, query col = g*16+ln
    f4 s[4][2] = {};
    __builtin_amdgcn_s_setprio(1);
#pragma unroll
    for (int ks = 0; ks < 2; ++ks)
#pragma unroll
      for (int ki = 0; ki < 4; ++ki) {
        bf16x8 kf = *(const bf16x8*)&sK[cur][(ki * 16 + ln) * 64 + (((ks * 4 + q) ^ sw) * 8)];
        s[ki][0] = mfma16(kf, qf[ks][0], s[ki][0]);
        s[ki][1] = mfma16(kf, qf[ks][1], s[ki][1]);
      }
    __builtin_amdgcn_s_setprio(0);

    // p = exp2(s); accumulate per-lane l; write P (wave-private rows)
#pragma unroll
    for (int g = 0; g < 2; ++g)
#pragma unroll
      for (int ki = 0; ki < 4; ++ki) {
        f4 sv = s[ki][g];
        float p0 = EXP2(sv[0]), p1 = EXP2(sv[1]);
        float p2 = EXP2(sv[2]), p3 = EXP2(sv[3]);
        if (g == 0) lsum0 += (p0 + p1) + (p2 + p3);
        else        lsum1 += (p0 + p1) + (p2 + p3);
        bf16x4 pk;
        pk[0] = (__bf16)p0; pk[1] = (__bf16)p1;
        pk[2] = (__bf16)p2; pk[3] = (__bf16)p3;
        *(bf16x4*)&sQP[(wq + g * 16 + ln) * 64 +
                       (((2 * ki + (q >> 1)) ^ sw) * 8) + (q & 1) * 4] = pk;
      }

    // O += P V  (A = P rows=query, B = V^T rows=d); same-wave P, no barrier
    __builtin_amdgcn_s_setprio(1);
#pragma unroll
    for (int ks = 0; ks < 2; ++ks) {
      bf16x8 vf[4];
#pragma unroll
      for (int j = 0; j < 4; ++j)
        vf[j] = *(const bf16x8*)&sV[cur][(j * 16 + ln) * 64 + (((ks * 4 + q) ^ sw) * 8)];
#pragma unroll
      for (int g = 0; g < 2; ++g) {
        bf16x8 pf = *(const bf16x8*)&sQP[(wq + g * 16 + ln) * 64 + (((ks * 4 + q) ^ sw) * 8)];
#pragma unroll
        for (int j = 0; j < 4; ++j)
          o[g][j] = mfma16(pf, vf[j], o[g][j]);
      }
    }
    __builtin_amdgcn_s_setprio(0);

    __syncthreads();   // drains vmcnt (prefetch) + lgkm; next buffer ready
  }

  // reduce l across the 4 q-quads (lanes with same ln), then finalize
#pragma unroll
  for (int g = 0; g < 2; ++g) {
    float lfull = (g == 0) ? lsum0 : lsum1;
    lfull += __shfl_xor(lfull, 16);
    lfull += __shfl_xor(lfull, 32);
#pragma unroll
    for (int r = 0; r < 4; ++r) {
      float lr = __shfl(lfull, q * 4 + r);
      float inv = 1.0f / lr;
      int token_row = qb * 256 + wq + g * 16 + q * 4 + r;
      size_t base = ((size_t)(bh >> 4) * NN + token_row) * CC + (bh & 15) * DD;
#pragma unroll
      for (int j = 0; j < 4; ++j)
        ctx[base + j * 16 + ln] = f2bf(o[g][j][r] * inv);
    }
  }
}

extern "C" void kernel_launch(void* const* d_in, const int* in_sizes, int n_in,
                              void* d_out, int out_size, void* d_ws, size_t ws_size,
                              hipStream_t stream) {
  const float* hs     = (const float*)d_in[0];
  const float* qkv_w  = (const float*)d_in[1];
  const float* qkv_b  = (const float*)d_in[2];
  const float* proj_w = (const float*)d_in[3];
  const float* proj_b = (const float*)d_in[4];

  // workspace layout (ushort elements)
  short* ws = (short*)d_ws;
  if (ws_size < 176160768ull) return;   // 168 MB needed
  short* Xbf = ws;                       // [16384][1024]
  short* Wq  = ws + 16777216;            // [3072][1024]
  short* Wp  = ws + 19922944;            // [1024][1024]
  short* Qm  = ws + 20971520;            // [bh][n][d]
  short* Km  = ws + 37748736;            // [bh][n][d]
  short* Vt  = ws + 54525952;            // [bh][d][n]  (written transposed by epilogue)
  short* Ctx = ws + 71303168;            // [16384][1024]

  cast_bf16<<<16384, 256, 0, stream>>>(hs, Xbf);
  transpose_cast<<<dim3(96, 32), 256, 0, stream>>>(qkv_w, Wq, 1024, 3072);
  transpose_cast<<<dim3(32, 32), 256, 0, stream>>>(proj_w, Wp, 1024, 1024);

  gemm_bt<1><<<dim3(24, 64), 512, 0, stream>>>(Xbf, Wq, qkv_b, nullptr, Qm,
                                               BN, 3 * CC, CC);
  attn<<<dim3(256, 4), 512, 0, stream>>>(Qm, Km, Vt, Ctx);
  gemm_bt<0><<<dim3(8, 64), 512, 0, stream>>>(Ctx, Wp, proj_b, (float*)d_out, nullptr,
                                              BN, CC, CC);
}

// Round 5
// 380.689 us; speedup vs baseline: 1.0744x; 1.0744x over previous
//
#include <hip/hip_runtime.h>

// ViTPose attention, B=16 N=1024 C=1024 H=16 D=64, fp32 in/out.
// bf16 MFMA pipeline: cast/transpose -> QKV GEMM -> flash attention (S^T form) -> proj GEMM.
// R10: GEMM back to the proven R7 2-phase body but BK=32 -> LDS 32 KB/block ->
// 4 blocks/CU (was 2): the 2-phase barrier drain is hidden by sibling blocks
// (R9 showed 1-block/CU coarse pipelining regresses; TLP is the lever).
// Attn: R7 body + softmax denominator folded into MFMA (l4 += pf x ones in the
// PV loop) - kills the lsum VALU chain and the whole shfl reduce at finalize.

#define BB 16
#define NN 1024
#define CC 1024
#define HH 16
#define DD 64
#define BN (BB * NN)          // 16384 tokens
#define HEADELEMS (256 * 1024 * 64)  // 16777216 elems per Q/K/V region

typedef float  f4     __attribute__((ext_vector_type(4)));
typedef __bf16 bf16x8 __attribute__((ext_vector_type(8)));
typedef __bf16 bf16x4 __attribute__((ext_vector_type(4)));
typedef short  s8v    __attribute__((ext_vector_type(8)));
typedef short  s4v    __attribute__((ext_vector_type(4)));
typedef short  s2v    __attribute__((ext_vector_type(2)));

#if __has_builtin(__builtin_amdgcn_exp2f)
#define EXP2(x) __builtin_amdgcn_exp2f(x)
#else
#define EXP2(x) exp2f(x)
#endif

__device__ __forceinline__ short f2bf(float x) {
  union { float f; unsigned u; } a; a.f = x;
  unsigned r = a.u + 0x7fffu + ((a.u >> 16) & 1u);   // RNE truncate (finite inputs)
  return (short)(r >> 16);
}

__device__ __forceinline__ void gl_lds16(const void* g, void* l) {
  __builtin_amdgcn_global_load_lds((__attribute__((address_space(1))) void*)g,
                                   (__attribute__((address_space(3))) void*)l,
                                   16, 0, 0);
}

__device__ __forceinline__ f4 mfma16(bf16x8 a, bf16x8 b, f4 c) {
  return __builtin_amdgcn_mfma_f32_16x16x32_bf16(a, b, c, 0, 0, 0);
}

// ---------------- elementwise fp32 -> bf16 cast ----------------
__global__ void cast_bf16(const float* __restrict__ x, short* __restrict__ y) {
  int i = (blockIdx.x * 256 + threadIdx.x) * 4;
  float4 v = *(const float4*)&x[i];
  s4v o;
  o[0] = f2bf(v.x); o[1] = f2bf(v.y); o[2] = f2bf(v.z); o[3] = f2bf(v.w);
  *(s4v*)&y[i] = o;
}

// ---------------- W [K][Nw] fp32 -> Wt [Nw][K] bf16 ----------------
__global__ void transpose_cast(const float* __restrict__ W, short* __restrict__ Wt,
                               int K, int Nw) {
  __shared__ float tile[32][33];
  int bx = blockIdx.x, by = blockIdx.y;
  int t = threadIdx.x;
  int tc = t & 31, tr = t >> 5;   // tr 0..7
#pragma unroll
  for (int i = 0; i < 4; ++i) {
    int r = tr + i * 8;
    tile[r][tc] = W[(size_t)(by * 32 + r) * Nw + bx * 32 + tc];
  }
  __syncthreads();
#pragma unroll
  for (int i = 0; i < 4; ++i) {
    int r = tr + i * 8;
    Wt[(size_t)(bx * 32 + r) * K + by * 32 + tc] = f2bf(tile[tc][r]);
  }
}

// ---------------- bf16 GEMM: C[M][N] = A[M][K] * Bt[N][K]^T + bias ----------------
// 128x128 block tile, BK=32, 256 threads = 4 waves in 2x2 of 64x64.
// LDS 32 KB/block -> 4 blocks/CU: the per-step barrier drain of one block is
// hidden by 3 sibling blocks' compute. One gl_lds16 wave-op stages 16 rows
// (lane>>2 = row, lane&3 = chunk, xor-swizzled by row&3); read side applies
// the matching (q ^ ln&3) slot. Bank math: 8 lanes per 4-bank group = 8-cycle
// minimum per b128, zero conflict cycles (same class as BK=64's measured 0).
#define GSTAGE(buf, kb)                                                        \
  {                                                                            \
    _Pragma("unroll")                                                          \
    for (int rblk = 0; rblk < 2; ++rblk) {                                     \
      int rbase = (w * 2 + rblk) * 16;                                         \
      gl_lds16(A + (size_t)(row0 + rbase + sr4) * K + (kb) + sc4 * 8,          \
               &la[buf][rbase * 32]);                                          \
      gl_lds16(Bt + (size_t)(col0 + rbase + sr4) * K + (kb) + sc4 * 8,         \
               &lb[buf][rbase * 32]);                                          \
    }                                                                          \
  }

template <int EPI>
__global__ __launch_bounds__(256, 4)
void gemm_bt(const short* __restrict__ A, const short* __restrict__ Bt,
             const float* __restrict__ bias, float* __restrict__ Cf,
             short* __restrict__ Cq, int M, int N, int K) {
  __shared__ short la[2][128 * 32];   // 8 KB x2
  __shared__ short lb[2][128 * 32];   // 8 KB x2   (32 KB total)
  const int t = threadIdx.x, lane = t & 63, w = t >> 6;
  // XCD-chunked swizzle + 8x8 sub-blocking (proven R7 mapping)
  int bid = blockIdx.y * gridDim.x + blockIdx.x;
  int xcd = bid & 7, sub = bid >> 3;
  int xg = sub >> 7, rem = sub & 127;
  int xb = xg * 8 + (rem & 7), yb = xcd * 16 + (rem >> 3);
  const int row0 = yb * 128, col0 = xb * 128;
  const int wm = (w & 1) * 64, wn = (w >> 1) * 64;
  const int q = lane >> 4, ln = lane & 15;
  const int sr4 = lane >> 2;               // row within 16-row group
  const int sc4 = (lane & 3) ^ (sr4 & 3);  // global 16B chunk (xor swizzle)
  f4 acc[4][4] = {};

  GSTAGE(0, 0);
  __syncthreads();
  int cur = 0;
  for (int kb = 0; kb < K; kb += 32, cur ^= 1) {
    if (kb + 32 < K) GSTAGE(cur ^ 1, kb + 32);
    const int swz = (q ^ (ln & 3)) * 8;   // swizzled chunk offset (shorts)
    bf16x8 af[4], bfr[4];
#pragma unroll
    for (int i = 0; i < 4; ++i) {
      af[i]  = *(const bf16x8*)&la[cur][(wm + i * 16 + ln) * 32 + swz];
      bfr[i] = *(const bf16x8*)&lb[cur][(wn + i * 16 + ln) * 32 + swz];
    }
    __builtin_amdgcn_s_setprio(1);
#pragma unroll
    for (int i = 0; i < 4; ++i)
#pragma unroll
      for (int j = 0; j < 4; ++j)
        acc[i][j] = mfma16(af[i], bfr[j], acc[i][j]);
    __builtin_amdgcn_s_setprio(0);
    __syncthreads();   // drains this step's prefetch (hidden by sibling blocks)
  }

#pragma unroll
  for (int i = 0; i < 4; ++i) {
    int rbase = row0 + wm + i * 16 + q * 4;
#pragma unroll
    for (int j = 0; j < 4; ++j) {
      int col = col0 + wn + j * 16 + ln;
      float bv = bias[col];
      if (EPI == 0) {
#pragma unroll
        for (int r2 = 0; r2 < 4; ++r2)
          Cf[(size_t)(rbase + r2) * N + col] = acc[i][j][r2] + bv;
      } else {
        int which = col >> 10, c = col & 1023;
        int h = c >> 6, d = c & 63;
        if (which == 2) {
          // V -> transposed layout [bh][d][n]; 4 consecutive tokens = s4v store
          int bh = (rbase >> 10) * HH + h;
          s4v vv;
#pragma unroll
          for (int r2 = 0; r2 < 4; ++r2) vv[r2] = f2bf(acc[i][j][r2] + bv);
          *(s4v*)&Cq[(size_t)2 * HEADELEMS + ((size_t)bh * DD + d) * NN + (rbase & 1023)] = vv;
        } else {
          float scale = (which == 0) ? 0.1803368801f : 1.0f;  // (1/8)*log2(e) for Q
#pragma unroll
          for (int r2 = 0; r2 < 4; ++r2) {
            int row = rbase + r2;                       // token
            int bh = (row >> 10) * HH + h;
            size_t idx = ((size_t)bh * NN + (row & 1023)) * DD + d;
            Cq[(size_t)which * HEADELEMS + idx] = f2bf((acc[i][j][r2] + bv) * scale);
          }
        }
      }
    }
  }
}

// ---------------- flash attention, S^T form, fixed-max softmax ----------------
// grid (256 bh, 4 qb). 512 threads = 8 waves; each wave owns 32 q rows
// (2 groups of 16 -> every K/V/P fragment read feeds 2 MFMAs).
// All LDS tiles: linear 64-short rows, 16B chunks XOR-swizzled by (row&7);
// every fragment row is 16k+ln so the swizzle is the lane constant ln&7.
// K from Km [bh][n][d]; V from Vt [bh][d][n] (written by QKV epilogue).
// K/V double-buffered, prefetch issued before compute, ONE barrier per kt.
// Scores carry (1/8)*log2e from Q pre-scale; fixed max=0 softmax (|s|<=~9).
// Softmax denominator via MFMA: l4[g] += pf x ones (C row layout == o's),
// so finalize divides per-lane with no shuffles; normalizer = sum of the
// same bf16 P used in the numerator (better matched than fp32 lsum).
__global__ __launch_bounds__(512, 4)
void attn(const short* __restrict__ Qg, const short* __restrict__ Kg,
          const short* __restrict__ Vtg, short* __restrict__ ctx) {
  __shared__ short sQP[256 * 64];     // 32 KB: Q tile at start, then P (wave-private rows)
  __shared__ short sK[2][64 * 64];    // 16 KB
  __shared__ short sV[2][64 * 64];    // 16 KB: V^T tile, row=d, col=m(key)
  const int t = threadIdx.x, lane = t & 63, w = t >> 6;
  const int bh = blockIdx.x, qb = blockIdx.y;
  const short* Qh = Qg + (size_t)bh * (NN * DD) + qb * 256 * DD;
  const short* Kh = Kg + (size_t)bh * (NN * DD);
  const short* Vh = Vtg + (size_t)bh * (NN * DD);   // [d][n]

  // --- stage Q tile [256][64]: 2048 chunks, DMA, inverse-swizzled source ---
#pragma unroll
  for (int k = 0; k < 4; ++k) {
    int i = t + k * 512;
    int r = i >> 3, c = i & 7;
    gl_lds16(Qh + r * DD + ((c ^ (r & 7)) * 8), &sQP[i * 8]);
  }
  // --- stage K/V tile 0 (512 chunks each, 1 per thread) ---
  const int sr = t >> 3, sc = t & 7;
  const int ssc = ((sc ^ (sr & 7)) * 8);      // swizzled chunk offset (shorts)
  gl_lds16(Kh + sr * DD + ssc, &sK[0][t * 8]);
  gl_lds16(Vh + (size_t)sr * NN + ssc, &sV[0][t * 8]);

  __syncthreads();   // drains vmcnt: Q + tile0 resident

  const int q = lane >> 4, ln = lane & 15;
  const int wq = w * 32;          // this wave's 32 query rows
  const int sw = ln & 7;          // fragment-row chunk swizzle

  // hoist Q fragments (own rows only); frees sQP for P
  bf16x8 qf[2][2];
#pragma unroll
  for (int ks = 0; ks < 2; ++ks)
#pragma unroll
    for (int g = 0; g < 2; ++g)
      qf[ks][g] = *(const bf16x8*)&sQP[(wq + g * 16 + ln) * 64 + (((ks * 4 + q) ^ sw) * 8)];

  bf16x8 onesb;
#pragma unroll
  for (int j = 0; j < 8; ++j) onesb[j] = (__bf16)1.0f;

  f4 o[2][4] = {};                // O[g][j]: row=q*4+r (query), col=j*16+ln (d)
  f4 l4[2] = {};                  // softmax denominators, same C-layout rows

  for (int kt = 0; kt < 16; ++kt) {
    const int cur = kt & 1;
    // prefetch next K/V tile into the other buffer (drained by end barrier)
    if (kt < 15) {
      const int nb = cur ^ 1;
      gl_lds16(Kh + (kt + 1) * 64 * DD + sr * DD + ssc, &sK[nb][t * 8]);
      gl_lds16(Vh + (size_t)sr * NN + (kt + 1) * 64 + ssc, &sV[nb][t * 8]);
    }

    // S^T = K Q^T : s[ki][g] has key row = ki*16+q*4+r, query col = g*16+ln
    f4 s[4][2] = {};
    __builtin_amdgcn_s_setprio(1);
#pragma unroll
    for (int ks = 0; ks < 2; ++ks)
#pragma unroll
      for (int ki = 0; ki < 4; ++ki) {
        bf16x8 kf = *(const bf16x8*)&sK[cur][(ki * 16 + ln) * 64 + (((ks * 4 + q) ^ sw) * 8)];
        s[ki][0] = mfma16(kf, qf[ks][0], s[ki][0]);
        s[ki][1] = mfma16(kf, qf[ks][1], s[ki][1]);
      }
    __builtin_amdgcn_s_setprio(0);

    // p = exp2(s); write P (wave-private rows); l accumulated via MFMA below
#pragma unroll
    for (int g = 0; g < 2; ++g)
#pragma unroll
      for (int ki = 0; ki < 4; ++ki) {
        f4 sv = s[ki][g];
        bf16x4 pk;
        pk[0] = (__bf16)EXP2(sv[0]); pk[1] = (__bf16)EXP2(sv[1]);
        pk[2] = (__bf16)EXP2(sv[2]); pk[3] = (__bf16)EXP2(sv[3]);
        *(bf16x4*)&sQP[(wq + g * 16 + ln) * 64 +
                       (((2 * ki + (q >> 1)) ^ sw) * 8) + (q & 1) * 4] = pk;
      }

    // O += P V  (A = P rows=query, B = V^T rows=d); same-wave P, no barrier
    __builtin_amdgcn_s_setprio(1);
#pragma unroll
    for (int ks = 0; ks < 2; ++ks) {
      bf16x8 vf[4];
#pragma unroll
      for (int j = 0; j < 4; ++j)
        vf[j] = *(const bf16x8*)&sV[cur][(j * 16 + ln) * 64 + (((ks * 4 + q) ^ sw) * 8)];
#pragma unroll
      for (int g = 0; g < 2; ++g) {
        bf16x8 pf = *(const bf16x8*)&sQP[(wq + g * 16 + ln) * 64 + (((ks * 4 + q) ^ sw) * 8)];
        l4[g] = mfma16(pf, onesb, l4[g]);   // denominator: rowsum of P
#pragma unroll
        for (int j = 0; j < 4; ++j)
          o[g][j] = mfma16(pf, vf[j], o[g][j]);
      }
    }
    __builtin_amdgcn_s_setprio(0);

    __syncthreads();   // drains vmcnt (prefetch) + lgkm; next buffer ready
  }

  // finalize: l4[g][r] is l for query row q*4+r (same C-layout as o) — no shuffles
#pragma unroll
  for (int g = 0; g < 2; ++g)
#pragma unroll
    for (int r = 0; r < 4; ++r) {
      float inv = 1.0f / l4[g][r];
      int token_row = qb * 256 + wq + g * 16 + q * 4 + r;
      size_t base = ((size_t)(bh >> 4) * NN + token_row) * CC + (bh & 15) * DD;
#pragma unroll
      for (int j = 0; j < 4; ++j)
        ctx[base + j * 16 + ln] = f2bf(o[g][j][r] * inv);
    }
}

extern "C" void kernel_launch(void* const* d_in, const int* in_sizes, int n_in,
                              void* d_out, int out_size, void* d_ws, size_t ws_size,
                              hipStream_t stream) {
  const float* hs     = (const float*)d_in[0];
  const float* qkv_w  = (const float*)d_in[1];
  const float* qkv_b  = (const float*)d_in[2];
  const float* proj_w = (const float*)d_in[3];
  const float* proj_b = (const float*)d_in[4];

  // workspace layout (ushort elements)
  short* ws = (short*)d_ws;
  if (ws_size < 176160768ull) return;   // 168 MB needed
  short* Xbf = ws;                       // [16384][1024]
  short* Wq  = ws + 16777216;            // [3072][1024]
  short* Wp  = ws + 19922944;            // [1024][1024]
  short* Qm  = ws + 20971520;            // [bh][n][d]
  short* Km  = ws + 37748736;            // [bh][n][d]
  short* Vt  = ws + 54525952;            // [bh][d][n]  (written transposed by epilogue)
  short* Ctx = ws + 71303168;            // [16384][1024]

  cast_bf16<<<16384, 256, 0, stream>>>(hs, Xbf);
  transpose_cast<<<dim3(96, 32), 256, 0, stream>>>(qkv_w, Wq, 1024, 3072);
  transpose_cast<<<dim3(32, 32), 256, 0, stream>>>(proj_w, Wp, 1024, 1024);

  gemm_bt<1><<<dim3(24, 128), 256, 0, stream>>>(Xbf, Wq, qkv_b, nullptr, Qm,
                                                BN, 3 * CC, CC);
  attn<<<dim3(256, 4), 512, 0, stream>>>(Qm, Km, Vt, Ctx);
  gemm_bt<0><<<dim3(8, 128), 256, 0, stream>>>(Ctx, Wp, proj_b, (float*)d_out, nullptr,
                                               BN, CC, CC);
}

// Round 6
// 378.334 us; speedup vs baseline: 1.0811x; 1.0062x over previous
//
#include <hip/hip_runtime.h>

// ViTPose attention, B=16 N=1024 C=1024 H=16 D=64, fp32 in/out.
// bf16 MFMA pipeline: cast/transpose -> QKV GEMM -> flash attention (S^T form) -> proj GEMM.
// R11: R10 + GEMM bank-conflict fix. At BK=32 the LDS row stride is 64 B =
// 16 banks, so bank group = 4*(row&1) + chunk; R10's chunk swizzle (row&3)
// correlated with row parity -> 2x quarter-phase conflicts (measured 1.26e7).
// Fix: swizzle by (row>>1)&3 -> groups 0..7 hit exactly twice per 16-lane
// quarter-phase (enumerated). Staging chunk = (lane&3)^((lane>>3)&3); read
// slot = q^((ln>>1)&3). Everything else identical to R10.

#define BB 16
#define NN 1024
#define CC 1024
#define HH 16
#define DD 64
#define BN (BB * NN)          // 16384 tokens
#define HEADELEMS (256 * 1024 * 64)  // 16777216 elems per Q/K/V region

typedef float  f4     __attribute__((ext_vector_type(4)));
typedef __bf16 bf16x8 __attribute__((ext_vector_type(8)));
typedef __bf16 bf16x4 __attribute__((ext_vector_type(4)));
typedef short  s8v    __attribute__((ext_vector_type(8)));
typedef short  s4v    __attribute__((ext_vector_type(4)));
typedef short  s2v    __attribute__((ext_vector_type(2)));

#if __has_builtin(__builtin_amdgcn_exp2f)
#define EXP2(x) __builtin_amdgcn_exp2f(x)
#else
#define EXP2(x) exp2f(x)
#endif

__device__ __forceinline__ short f2bf(float x) {
  union { float f; unsigned u; } a; a.f = x;
  unsigned r = a.u + 0x7fffu + ((a.u >> 16) & 1u);   // RNE truncate (finite inputs)
  return (short)(r >> 16);
}

__device__ __forceinline__ void gl_lds16(const void* g, void* l) {
  __builtin_amdgcn_global_load_lds((__attribute__((address_space(1))) void*)g,
                                   (__attribute__((address_space(3))) void*)l,
                                   16, 0, 0);
}

__device__ __forceinline__ f4 mfma16(bf16x8 a, bf16x8 b, f4 c) {
  return __builtin_amdgcn_mfma_f32_16x16x32_bf16(a, b, c, 0, 0, 0);
}

// ---------------- elementwise fp32 -> bf16 cast ----------------
__global__ void cast_bf16(const float* __restrict__ x, short* __restrict__ y) {
  int i = (blockIdx.x * 256 + threadIdx.x) * 4;
  float4 v = *(const float4*)&x[i];
  s4v o;
  o[0] = f2bf(v.x); o[1] = f2bf(v.y); o[2] = f2bf(v.z); o[3] = f2bf(v.w);
  *(s4v*)&y[i] = o;
}

// ---------------- W [K][Nw] fp32 -> Wt [Nw][K] bf16 ----------------
__global__ void transpose_cast(const float* __restrict__ W, short* __restrict__ Wt,
                               int K, int Nw) {
  __shared__ float tile[32][33];
  int bx = blockIdx.x, by = blockIdx.y;
  int t = threadIdx.x;
  int tc = t & 31, tr = t >> 5;   // tr 0..7
#pragma unroll
  for (int i = 0; i < 4; ++i) {
    int r = tr + i * 8;
    tile[r][tc] = W[(size_t)(by * 32 + r) * Nw + bx * 32 + tc];
  }
  __syncthreads();
#pragma unroll
  for (int i = 0; i < 4; ++i) {
    int r = tr + i * 8;
    Wt[(size_t)(bx * 32 + r) * K + by * 32 + tc] = f2bf(tile[tc][r]);
  }
}

// ---------------- bf16 GEMM: C[M][N] = A[M][K] * Bt[N][K]^T + bias ----------------
// 128x128 block tile, BK=32, 256 threads = 4 waves in 2x2 of 64x64.
// LDS 32 KB/block -> 4 blocks/CU; per-step barrier drain hidden by siblings.
// Bank math (64 B row stride = 16 banks): ds_read_b128 bank group =
// (4*(row&1) + slot) mod 8; slot swizzle uses (row>>1)&3 so a 16-lane
// quarter-phase covers all 8 groups exactly twice (conflict-free minimum).
// LDS slot s of row r holds global chunk s ^ ((r>>1)&3).
#define GSTAGE(buf, kb)                                                        \
  {                                                                            \
    _Pragma("unroll")                                                          \
    for (int rblk = 0; rblk < 2; ++rblk) {                                     \
      int rbase = (w * 2 + rblk) * 16;                                         \
      gl_lds16(A + (size_t)(row0 + rbase + sr4) * K + (kb) + sc4 * 8,          \
               &la[buf][rbase * 32]);                                          \
      gl_lds16(Bt + (size_t)(col0 + rbase + sr4) * K + (kb) + sc4 * 8,         \
               &lb[buf][rbase * 32]);                                          \
    }                                                                          \
  }

template <int EPI>
__global__ __launch_bounds__(256, 4)
void gemm_bt(const short* __restrict__ A, const short* __restrict__ Bt,
             const float* __restrict__ bias, float* __restrict__ Cf,
             short* __restrict__ Cq, int M, int N, int K) {
  __shared__ short la[2][128 * 32];   // 8 KB x2
  __shared__ short lb[2][128 * 32];   // 8 KB x2   (32 KB total)
  const int t = threadIdx.x, lane = t & 63, w = t >> 6;
  // XCD-chunked swizzle + 8x8 sub-blocking (proven R7 mapping)
  int bid = blockIdx.y * gridDim.x + blockIdx.x;
  int xcd = bid & 7, sub = bid >> 3;
  int xg = sub >> 7, rem = sub & 127;
  int xb = xg * 8 + (rem & 7), yb = xcd * 16 + (rem >> 3);
  const int row0 = yb * 128, col0 = xb * 128;
  const int wm = (w & 1) * 64, wn = (w >> 1) * 64;
  const int q = lane >> 4, ln = lane & 15;
  const int sr4 = lane >> 2;                        // row within 16-row group
  const int sc4 = (lane & 3) ^ ((lane >> 3) & 3);  // global chunk (row>>1 swizzle)
  f4 acc[4][4] = {};

  GSTAGE(0, 0);
  __syncthreads();
  int cur = 0;
  for (int kb = 0; kb < K; kb += 32, cur ^= 1) {
    if (kb + 32 < K) GSTAGE(cur ^ 1, kb + 32);
    const int swz = (q ^ ((ln >> 1) & 3)) * 8;   // swizzled slot offset (shorts)
    bf16x8 af[4], bfr[4];
#pragma unroll
    for (int i = 0; i < 4; ++i) {
      af[i]  = *(const bf16x8*)&la[cur][(wm + i * 16 + ln) * 32 + swz];
      bfr[i] = *(const bf16x8*)&lb[cur][(wn + i * 16 + ln) * 32 + swz];
    }
    __builtin_amdgcn_s_setprio(1);
#pragma unroll
    for (int i = 0; i < 4; ++i)
#pragma unroll
      for (int j = 0; j < 4; ++j)
        acc[i][j] = mfma16(af[i], bfr[j], acc[i][j]);
    __builtin_amdgcn_s_setprio(0);
    __syncthreads();   // drains this step's prefetch (hidden by sibling blocks)
  }

#pragma unroll
  for (int i = 0; i < 4; ++i) {
    int rbase = row0 + wm + i * 16 + q * 4;
#pragma unroll
    for (int j = 0; j < 4; ++j) {
      int col = col0 + wn + j * 16 + ln;
      float bv = bias[col];
      if (EPI == 0) {
#pragma unroll
        for (int r2 = 0; r2 < 4; ++r2)
          Cf[(size_t)(rbase + r2) * N + col] = acc[i][j][r2] + bv;
      } else {
        int which = col >> 10, c = col & 1023;
        int h = c >> 6, d = c & 63;
        if (which == 2) {
          // V -> transposed layout [bh][d][n]; 4 consecutive tokens = s4v store
          int bh = (rbase >> 10) * HH + h;
          s4v vv;
#pragma unroll
          for (int r2 = 0; r2 < 4; ++r2) vv[r2] = f2bf(acc[i][j][r2] + bv);
          *(s4v*)&Cq[(size_t)2 * HEADELEMS + ((size_t)bh * DD + d) * NN + (rbase & 1023)] = vv;
        } else {
          float scale = (which == 0) ? 0.1803368801f : 1.0f;  // (1/8)*log2(e) for Q
#pragma unroll
          for (int r2 = 0; r2 < 4; ++r2) {
            int row = rbase + r2;                       // token
            int bh = (row >> 10) * HH + h;
            size_t idx = ((size_t)bh * NN + (row & 1023)) * DD + d;
            Cq[(size_t)which * HEADELEMS + idx] = f2bf((acc[i][j][r2] + bv) * scale);
          }
        }
      }
    }
  }
}

// ---------------- flash attention, S^T form, fixed-max softmax ----------------
// grid (256 bh, 4 qb). 512 threads = 8 waves; each wave owns 32 q rows
// (2 groups of 16 -> every K/V/P fragment read feeds 2 MFMAs).
// All LDS tiles: linear 64-short rows (128 B = full 32 banks -> bank group
// = chunk, row drops out: balanced), 16B chunks XOR-swizzled by (row&7).
// K from Km [bh][n][d]; V from Vt [bh][d][n] (written by QKV epilogue).
// K/V double-buffered, prefetch issued before compute, ONE barrier per kt.
// Scores carry (1/8)*log2e from Q pre-scale; fixed max=0 softmax (|s|<=~9).
// Softmax denominator via MFMA: l4[g] += pf x ones (C row layout == o's),
// so finalize divides per-lane with no shuffles.
__global__ __launch_bounds__(512, 4)
void attn(const short* __restrict__ Qg, const short* __restrict__ Kg,
          const short* __restrict__ Vtg, short* __restrict__ ctx) {
  __shared__ short sQP[256 * 64];     // 32 KB: Q tile at start, then P (wave-private rows)
  __shared__ short sK[2][64 * 64];    // 16 KB
  __shared__ short sV[2][64 * 64];    // 16 KB: V^T tile, row=d, col=m(key)
  const int t = threadIdx.x, lane = t & 63, w = t >> 6;
  const int bh = blockIdx.x, qb = blockIdx.y;
  const short* Qh = Qg + (size_t)bh * (NN * DD) + qb * 256 * DD;
  const short* Kh = Kg + (size_t)bh * (NN * DD);
  const short* Vh = Vtg + (size_t)bh * (NN * DD);   // [d][n]

  // --- stage Q tile [256][64]: 2048 chunks, DMA, inverse-swizzled source ---
#pragma unroll
  for (int k = 0; k < 4; ++k) {
    int i = t + k * 512;
    int r = i >> 3, c = i & 7;
    gl_lds16(Qh + r * DD + ((c ^ (r & 7)) * 8), &sQP[i * 8]);
  }
  // --- stage K/V tile 0 (512 chunks each, 1 per thread) ---
  const int sr = t >> 3, sc = t & 7;
  const int ssc = ((sc ^ (sr & 7)) * 8);      // swizzled chunk offset (shorts)
  gl_lds16(Kh + sr * DD + ssc, &sK[0][t * 8]);
  gl_lds16(Vh + (size_t)sr * NN + ssc, &sV[0][t * 8]);

  __syncthreads();   // drains vmcnt: Q + tile0 resident

  const int q = lane >> 4, ln = lane & 15;
  const int wq = w * 32;          // this wave's 32 query rows
  const int sw = ln & 7;          // fragment-row chunk swizzle

  // hoist Q fragments (own rows only); frees sQP for P
  bf16x8 qf[2][2];
#pragma unroll
  for (int ks = 0; ks < 2; ++ks)
#pragma unroll
    for (int g = 0; g < 2; ++g)
      qf[ks][g] = *(const bf16x8*)&sQP[(wq + g * 16 + ln) * 64 + (((ks * 4 + q) ^ sw) * 8)];

  bf16x8 onesb;
#pragma unroll
  for (int j = 0; j < 8; ++j) onesb[j] = (__bf16)1.0f;

  f4 o[2][4] = {};                // O[g][j]: row=q*4+r (query), col=j*16+ln (d)
  f4 l4[2] = {};                  // softmax denominators, same C-layout rows

  for (int kt = 0; kt < 16; ++kt) {
    const int cur = kt & 1;
    // prefetch next K/V tile into the other buffer (drained by end barrier)
    if (kt < 15) {
      const int nb = cur ^ 1;
      gl_lds16(Kh + (kt + 1) * 64 * DD + sr * DD + ssc, &sK[nb][t * 8]);
      gl_lds16(Vh + (size_t)sr * NN + (kt + 1) * 64 + ssc, &sV[nb][t * 8]);
    }

    // S^T = K Q^T : s[ki][g] has key row = ki*16+q*4+r, query col = g*16+ln
    f4 s[4][2] = {};
    __builtin_amdgcn_s_setprio(1);
#pragma unroll
    for (int ks = 0; ks < 2; ++ks)
#pragma unroll
      for (int ki = 0; ki < 4; ++ki) {
        bf16x8 kf = *(const bf16x8*)&sK[cur][(ki * 16 + ln) * 64 + (((ks * 4 + q) ^ sw) * 8)];
        s[ki][0] = mfma16(kf, qf[ks][0], s[ki][0]);
        s[ki][1] = mfma16(kf, qf[ks][1], s[ki][1]);
      }
    __builtin_amdgcn_s_setprio(0);

    // p = exp2(s); write P (wave-private rows); l accumulated via MFMA below
#pragma unroll
    for (int g = 0; g < 2; ++g)
#pragma unroll
      for (int ki = 0; ki < 4; ++ki) {
        f4 sv = s[ki][g];
        bf16x4 pk;
        pk[0] = (__bf16)EXP2(sv[0]); pk[1] = (__bf16)EXP2(sv[1]);
        pk[2] = (__bf16)EXP2(sv[2]); pk[3] = (__bf16)EXP2(sv[3]);
        *(bf16x4*)&sQP[(wq + g * 16 + ln) * 64 +
                       (((2 * ki + (q >> 1)) ^ sw) * 8) + (q & 1) * 4] = pk;
      }

    // O += P V  (A = P rows=query, B = V^T rows=d); same-wave P, no barrier
    __builtin_amdgcn_s_setprio(1);
#pragma unroll
    for (int ks = 0; ks < 2; ++ks) {
      bf16x8 vf[4];
#pragma unroll
      for (int j = 0; j < 4; ++j)
        vf[j] = *(const bf16x8*)&sV[cur][(j * 16 + ln) * 64 + (((ks * 4 + q) ^ sw) * 8)];
#pragma unroll
      for (int g = 0; g < 2; ++g) {
        bf16x8 pf = *(const bf16x8*)&sQP[(wq + g * 16 + ln) * 64 + (((ks * 4 + q) ^ sw) * 8)];
        l4[g] = mfma16(pf, onesb, l4[g]);   // denominator: rowsum of P
#pragma unroll
        for (int j = 0; j < 4; ++j)
          o[g][j] = mfma16(pf, vf[j], o[g][j]);
      }
    }
    __builtin_amdgcn_s_setprio(0);

    __syncthreads();   // drains vmcnt (prefetch) + lgkm; next buffer ready
  }

  // finalize: l4[g][r] is l for query row q*4+r (same C-layout as o) — no shuffles
#pragma unroll
  for (int g = 0; g < 2; ++g)
#pragma unroll
    for (int r = 0; r < 4; ++r) {
      float inv = 1.0f / l4[g][r];
      int token_row = qb * 256 + wq + g * 16 + q * 4 + r;
      size_t base = ((size_t)(bh >> 4) * NN + token_row) * CC + (bh & 15) * DD;
#pragma unroll
      for (int j = 0; j < 4; ++j)
        ctx[base + j * 16 + ln] = f2bf(o[g][j][r] * inv);
    }
}

extern "C" void kernel_launch(void* const* d_in, const int* in_sizes, int n_in,
                              void* d_out, int out_size, void* d_ws, size_t ws_size,
                              hipStream_t stream) {
  const float* hs     = (const float*)d_in[0];
  const float* qkv_w  = (const float*)d_in[1];
  const float* qkv_b  = (const float*)d_in[2];
  const float* proj_w = (const float*)d_in[3];
  const float* proj_b = (const float*)d_in[4];

  // workspace layout (ushort elements)
  short* ws = (short*)d_ws;
  if (ws_size < 176160768ull) return;   // 168 MB needed
  short* Xbf = ws;                       // [16384][1024]
  short* Wq  = ws + 16777216;            // [3072][1024]
  short* Wp  = ws + 19922944;            // [1024][1024]
  short* Qm  = ws + 20971520;            // [bh][n][d]
  short* Km  = ws + 37748736;            // [bh][n][d]
  short* Vt  = ws + 54525952;            // [bh][d][n]  (written transposed by epilogue)
  short* Ctx = ws + 71303168;            // [16384][1024]

  cast_bf16<<<16384, 256, 0, stream>>>(hs, Xbf);
  transpose_cast<<<dim3(96, 32), 256, 0, stream>>>(qkv_w, Wq, 1024, 3072);
  transpose_cast<<<dim3(32, 32), 256, 0, stream>>>(proj_w, Wp, 1024, 1024);

  gemm_bt<1><<<dim3(24, 128), 256, 0, stream>>>(Xbf, Wq, qkv_b, nullptr, Qm,
                                                BN, 3 * CC, CC);
  attn<<<dim3(256, 4), 512, 0, stream>>>(Qm, Km, Vt, Ctx);
  gemm_bt<0><<<dim3(8, 128), 256, 0, stream>>>(Ctx, Wp, proj_b, (float*)d_out, nullptr,
                                               BN, CC, CC);
}